// Round 8
// baseline (752.991 us; speedup 1.0000x reference)
//
#include <hip/hip_runtime.h>
#include <hip/hip_bf16.h>

// TemporalAttention fused kernel for MI355X (gfx950), round 8.
// Persistent blocks (grid 256 = 1/CU), round-6 verified compute body, with:
//  - X staged as f32 via __builtin_amdgcn_global_load_lds (ZERO VGPRs --
//    fixes round-7's reg-staged-prefetch spill death), double-buffered.
//  - Source-address swizzle (m173 pattern) + 32B row pad => conflict-free
//    ds_read_b128 of X fragments (verified bank algebra).
//  - Next sequence's X issued right after the last X read of the current
//    one; lands under PV + phaseC + epilogue. Loop-top __syncthreads()
//    (full vmcnt drain) makes it visible.
//  - launch_bounds(512,1): 256-VGPR budget, no spills, deeper scheduling;
//    LDS 132KB limits to 1 block/CU regardless.

namespace {

constexpr int S_LEN = 64;
constexpr int DM    = 256;
constexpr int SD    = S_LEN * DM;      // 16384 elements per sequence
constexpr int NQKV  = 3 * DM * DM;
constexpr int XS    = 264;             // f32 row stride in LDS (256 + 8 pad)
constexpr int XBUF  = 64 * XS;         // 16896 floats per buffer (66 KB)

typedef float f32x4 __attribute__((ext_vector_type(4)));
typedef short s16x8 __attribute__((ext_vector_type(8)));

union BF2 { __hip_bfloat162 h; unsigned u; };
__device__ __forceinline__ unsigned pkbf2(float a, float b) {
  float2 t; t.x = a; t.y = b;
  BF2 cv; cv.h = __float22bfloat162_rn(t);
  return cv.u;
}

// In-register fragment transpose (verified rounds 3-7).
__device__ __forceinline__ s16x8 xpose_frag(f32x4 a0, f32x4 a1, int c, int g) {
  const int src0 = ((g & 1) << 5) + c;
  const int src1 = src0 + 16;
  unsigned p00 = pkbf2(a0[0], a0[1]);
  unsigned p01 = pkbf2(a0[2], a0[3]);
  unsigned p10 = pkbf2(a1[0], a1[1]);
  unsigned p11 = pkbf2(a1[2], a1[3]);
  const bool hi = (g & 2) != 0;
  unsigned w0a = (unsigned)__shfl((int)p00, src0);
  unsigned w0b = (unsigned)__shfl((int)p10, src0);
  unsigned w1a = (unsigned)__shfl((int)p01, src0);
  unsigned w1b = (unsigned)__shfl((int)p11, src0);
  unsigned w2a = (unsigned)__shfl((int)p00, src1);
  unsigned w2b = (unsigned)__shfl((int)p10, src1);
  unsigned w3a = (unsigned)__shfl((int)p01, src1);
  unsigned w3b = (unsigned)__shfl((int)p11, src1);
  union { s16x8 v; unsigned u[4]; } r;
  r.u[0] = hi ? w0b : w0a;
  r.u[1] = hi ? w1b : w1a;
  r.u[2] = hi ? w2b : w2a;
  r.u[3] = hi ? w3b : w3a;
  return r.v;
}

// X fragment: 8 consecutive f32 of row `row` starting at col `kof` (multiple
// of 4), from the source-swizzled padded LDS image, packed to bf16.
__device__ __forceinline__ s16x8 ldx(const float* __restrict__ xbuf, int row, int kof) {
  const int s  = row & 7;
  const int u0 = kof >> 2;
  f32x4 lo = *(const f32x4*)&xbuf[row * XS + (((u0)     ^ s) << 2)];
  f32x4 hi = *(const f32x4*)&xbuf[row * XS + (((u0 + 1) ^ s) << 2)];
  union { s16x8 v; unsigned u[4]; } r;
  r.u[0] = pkbf2(lo[0], lo[1]); r.u[1] = pkbf2(lo[2], lo[3]);
  r.u[2] = pkbf2(hi[0], hi[1]); r.u[3] = pkbf2(hi[2], hi[3]);
  return r.v;
}

// Async-stage one sequence's X (f32) into an LDS buffer. Wave w stages rows
// 8w..8w+7; one global_load_lds per row (64 lanes x 16B = 1KB = one row).
// Per-lane SOURCE is swizzled so that ldx()'s XOR read finds its data.
__device__ __forceinline__ void stage_x(const float* __restrict__ xb,
                                        float* __restrict__ dst, int w, int l) {
#pragma unroll
  for (int i = 0; i < 8; ++i) {
    const int row = 8 * w + i;
    const float* src = xb + row * 256 + ((l ^ (row & 7)) << 2);
    float* d = dst + row * XS;
    __builtin_amdgcn_global_load_lds(
        (const __attribute__((address_space(1))) unsigned int*)src,
        (__attribute__((address_space(3))) unsigned int*)d, 16, 0, 0);
  }
}

} // namespace

// ---- prep: f32 weights -> bf16 in workspace ----
__global__ void ta_prep_weights(const float* __restrict__ wqkv,
                                const float* __restrict__ wproj,
                                unsigned short* __restrict__ wsb) {
  const int i = (blockIdx.x * 256 + (int)threadIdx.x) * 4;
  f32x4 v = (i < NQKV) ? *(const f32x4*)(wqkv + i)
                       : *(const f32x4*)(wproj + (i - NQKV));
  unsigned u0 = pkbf2(v[0], v[1]);
  unsigned u1 = pkbf2(v[2], v[3]);
  *(uint2*)(wsb + i) = make_uint2(u0, u1);
}

__global__ void __launch_bounds__(512, 1)
ta_fused_kernel(const float* __restrict__ x,
                const unsigned short* __restrict__ wq_bf,   // [768][256] bf16
                const float* __restrict__ bqkv,
                const unsigned short* __restrict__ wp_bf,   // [256][256] bf16
                const float* __restrict__ bproj,
                float* __restrict__ out, int bn_total, int nb)
{
  // 2 x 66KB X buffers (f32, padded+source-swizzled). Overlays on the CURRENT
  // buffer once X is dead: att bf16 [64][256] in floats [0,8192);
  // epilogue f32 [32][256] in floats [8192,16384).
  __shared__ __align__(16) float ldsx[2][XBUF];

  const int tid = (int)threadIdx.x;
  const int w = tid >> 6;       // wave 0..7 = head
  const int l = tid & 63;
  const int g = l >> 4;
  const int c = l & 15;
  const int c7s = (c & 7) << 3;
  const int h = w;

  const int bn0 = blockIdx.x;
  if (bn0 >= bn_total) return;

  // prologue: issue stage of first sequence into buffer 0 (async)
  stage_x(x + (size_t)bn0 * SD, ldsx[0], w, l);

  int cur = 0;
#pragma unroll 1
  for (int bn = bn0; bn < bn_total; bn += nb, cur ^= 1) {
    float* __restrict__ xcur = ldsx[cur];
    float* __restrict__ xnxt = ldsx[cur ^ 1];
    const bool pf = (bn + nb) < bn_total;            // block-uniform

    __syncthreads();   // drains vmcnt (stage loads) + barrier: X visible

    // ---- sweep 1: Q^T, K^T = Wq/Wk @ X^T for head h ----
    f32x4 aq[2][4], ak[2][4];
#pragma unroll
    for (int t = 0; t < 2; ++t)
#pragma unroll
      for (int nj = 0; nj < 4; ++nj) {
        aq[t][nj] = f32x4{0.f, 0.f, 0.f, 0.f};
        ak[t][nj] = f32x4{0.f, 0.f, 0.f, 0.f};
      }
#pragma unroll
    for (int ks = 0; ks < 8; ++ks) {
      const int kof = ks * 32 + g * 8;
      s16x8 bx[4];
#pragma unroll
      for (int nj = 0; nj < 4; ++nj)
        bx[nj] = ldx(xcur, 16 * nj + c, kof);
#pragma unroll
      for (int t = 0; t < 2; ++t) {
        s16x8 awq = *(const s16x8*)&wq_bf[(size_t)((2 * h + t) * 16 + c) * DM + kof];
        s16x8 awk = *(const s16x8*)&wq_bf[(size_t)((256 + 32 * h + 16 * t) + c) * DM + kof];
#pragma unroll
        for (int nj = 0; nj < 4; ++nj) {
          aq[t][nj] = __builtin_amdgcn_mfma_f32_16x16x32_bf16(awq, bx[nj], aq[t][nj], 0, 0, 0);
          ak[t][nj] = __builtin_amdgcn_mfma_f32_16x16x32_bf16(awk, bx[nj], ak[t][nj], 0, 0, 0);
        }
      }
    }
#pragma unroll
    for (int t = 0; t < 2; ++t) {
      f32x4 bq = *(const f32x4*)(bqkv + (2 * h + t) * 16 + 4 * g);
      f32x4 bk = *(const f32x4*)(bqkv + 256 + 32 * h + 16 * t + 4 * g);
#pragma unroll
      for (int nj = 0; nj < 4; ++nj) {
        aq[t][nj] += bq;
        ak[t][nj] += bk;
      }
    }

    // ---- Q,K fragments (in-register transpose) ----
    s16x8 qa[4], ka[4];
#pragma unroll
    for (int i = 0; i < 4; ++i) {
      qa[i] = xpose_frag(aq[0][i], aq[1][i], c, g);
      ka[i] = xpose_frag(ak[0][i], ak[1][i], c, g);
    }

    // ---- S^T = K @ Q^T ----
    f32x4 sa[4][4];
#pragma unroll
    for (int ki = 0; ki < 4; ++ki)
#pragma unroll
      for (int qi = 0; qi < 4; ++qi) {
        f32x4 z = f32x4{0.f, 0.f, 0.f, 0.f};
        sa[ki][qi] = __builtin_amdgcn_mfma_f32_16x16x32_bf16(ka[ki], qa[qi], z, 0, 0, 0);
      }

    // ---- softmax over keys ----
    const float sc = 0.17677669529663687f * 1.4426950408889634f;
    float inv[4];
#pragma unroll
    for (int qi = 0; qi < 4; ++qi) {
      float m = sa[0][qi][0];
#pragma unroll
      for (int ki = 0; ki < 4; ++ki)
#pragma unroll
        for (int r = 0; r < 4; ++r) m = fmaxf(m, sa[ki][qi][r]);
      m = fmaxf(m, __shfl_xor(m, 16));
      m = fmaxf(m, __shfl_xor(m, 32));
      float s = 0.0f;
#pragma unroll
      for (int ki = 0; ki < 4; ++ki)
#pragma unroll
        for (int r = 0; r < 4; ++r) {
          float pv = exp2f((sa[ki][qi][r] - m) * sc);
          sa[ki][qi][r] = pv;
          s += pv;
        }
      s += __shfl_xor(s, 16);
      s += __shfl_xor(s, 32);
      inv[qi] = 1.0f / s;
    }

    // ---- P fragments (normalized, in-register transpose) ----
    s16x8 pa[4][2];
#pragma unroll
    for (int mi = 0; mi < 4; ++mi) {
      const float iv = inv[mi];
#pragma unroll
      for (int ks2 = 0; ks2 < 2; ++ks2) {
        f32x4 v0 = sa[2 * ks2][mi] * iv;
        f32x4 v1 = sa[2 * ks2 + 1][mi] * iv;
        pa[mi][ks2] = xpose_frag(v0, v1, c, g);
      }
    }

    // ---- sweep 2: V = X @ Wv^T -> (seq = 16mt+4g+r, d = 16t+c) ----
    f32x4 av[4][2];
#pragma unroll
    for (int mt = 0; mt < 4; ++mt)
#pragma unroll
      for (int t = 0; t < 2; ++t) av[mt][t] = f32x4{0.f, 0.f, 0.f, 0.f};
#pragma unroll
    for (int ks = 0; ks < 8; ++ks) {
      const int kof = ks * 32 + g * 8;
      s16x8 bx[4];
#pragma unroll
      for (int mt = 0; mt < 4; ++mt)
        bx[mt] = ldx(xcur, 16 * mt + c, kof);
#pragma unroll
      for (int t = 0; t < 2; ++t) {
        s16x8 wv = *(const s16x8*)&wq_bf[(size_t)(512 + 32 * h + 16 * t + c) * DM + kof];
#pragma unroll
        for (int mt = 0; mt < 4; ++mt)
          av[mt][t] = __builtin_amdgcn_mfma_f32_16x16x32_bf16(bx[mt], wv, av[mt][t], 0, 0, 0);
      }
    }

    // ---- issue next sequence's X stage (async, zero-VGPR) ----
    // This wave's X reads are done; dest buffer is 2-iterations-old (dead).
    if (pf) stage_x(x + (size_t)(bn + nb) * SD, xnxt, w, l);

    // V bias (d-col = 16t + c)
    {
      const float bv0 = bqkv[512 + 32 * h + c];
      const float bv1 = bqkv[512 + 32 * h + 16 + c];
#pragma unroll
      for (int mt = 0; mt < 4; ++mt)
#pragma unroll
        for (int r = 0; r < 4; ++r) {
          av[mt][0][r] += bv0;
          av[mt][1][r] += bv1;
        }
    }

    // ---- V fragments (in-register transpose) ----
    s16x8 vb[2][2];
#pragma unroll
    for (int nd = 0; nd < 2; ++nd)
#pragma unroll
      for (int ks2 = 0; ks2 < 2; ++ks2)
        vb[nd][ks2] = xpose_frag(av[2 * ks2][nd], av[2 * ks2 + 1][nd], c, g);

    // ---- O = P @ V ----
    f32x4 oa[4][2];
#pragma unroll
    for (int mi = 0; mi < 4; ++mi)
#pragma unroll
      for (int nd = 0; nd < 2; ++nd) oa[mi][nd] = f32x4{0.f, 0.f, 0.f, 0.f};
#pragma unroll
    for (int ks2 = 0; ks2 < 2; ++ks2)
#pragma unroll
      for (int mi = 0; mi < 4; ++mi)
#pragma unroll
        for (int nd = 0; nd < 2; ++nd)
          oa[mi][nd] = __builtin_amdgcn_mfma_f32_16x16x32_bf16(pa[mi][ks2], vb[nd][ks2], oa[mi][nd], 0, 0, 0);

    unsigned obp[4][2][2];
#pragma unroll
    for (int mi = 0; mi < 4; ++mi)
#pragma unroll
      for (int nd = 0; nd < 2; ++nd) {
        obp[mi][nd][0] = pkbf2(oa[mi][nd][0], oa[mi][nd][1]);
        obp[mi][nd][1] = pkbf2(oa[mi][nd][2], oa[mi][nd][3]);
      }

    __syncthreads();  // ALL waves done reading current X

    // scatter O into att[row][feat] overlaying current X buffer
    unsigned short* __restrict__ att = (unsigned short*)xcur;
#pragma unroll
    for (int mi = 0; mi < 4; ++mi)
#pragma unroll
      for (int nd = 0; nd < 2; ++nd)
#pragma unroll
        for (int r = 0; r < 4; ++r) {
          const int q = 16 * mi + 4 * g + r;
          const int feat = h * 32 + 16 * nd + c;
          unsigned val = obp[mi][nd][r >> 1] >> (16 * (r & 1));
          att[(q * 256 + feat) ^ ((q & 7) << 3)] = (unsigned short)val;
        }
    __syncthreads();

    // ---- Phase C: out^T = Wproj @ att^T (2 e-tiles per wave) ----
    f32x4 pacc[2][4];
#pragma unroll
    for (int ti = 0; ti < 2; ++ti)
#pragma unroll
      for (int nj = 0; nj < 4; ++nj) pacc[ti][nj] = f32x4{0.f, 0.f, 0.f, 0.f};

#pragma unroll
    for (int ks = 0; ks < 8; ++ks) {
      const int kof = ks * 32 + 8 * g;
      s16x8 bx[4];
#pragma unroll
      for (int nj = 0; nj < 4; ++nj) {
        const int row = 16 * nj + c;
        bx[nj] = *(const s16x8*)&att[(row * 256 + kof) ^ c7s];
      }
#pragma unroll
      for (int ti = 0; ti < 2; ++ti) {
        const int e = (2 * w + ti) * 16 + c;
        s16x8 aw = *(const s16x8*)&wp_bf[(size_t)e * DM + kof];
#pragma unroll
        for (int nj = 0; nj < 4; ++nj)
          pacc[ti][nj] = __builtin_amdgcn_mfma_f32_16x16x32_bf16(aw, bx[nj], pacc[ti][nj], 0, 0, 0);
      }
    }

    __syncthreads();  // att reads done

    // ---- epilogue: two 32-row f32 halves in [8192,16384) of current buffer ----
    float* ldsf = xcur + 8192;
    float* __restrict__ ob = out + (size_t)bn * SD;
#pragma unroll
    for (int H = 0; H < 2; ++H) {
#pragma unroll
      for (int ti = 0; ti < 2; ++ti) {
        const int e0 = (2 * w + ti) * 16 + 4 * g;
        f32x4 bp = *(const f32x4*)(bproj + e0);
#pragma unroll
        for (int nj = 2 * H; nj < 2 * H + 2; ++nj) {
          const int lr = 16 * (nj - 2 * H) + c;
          f32x4 v;
          v[0] = pacc[ti][nj][0] + bp[0];
          v[1] = pacc[ti][nj][1] + bp[1];
          v[2] = pacc[ti][nj][2] + bp[2];
          v[3] = pacc[ti][nj][3] + bp[3];
          *(f32x4*)&ldsf[(lr * 256 + e0) ^ ((lr & 7) << 2)] = v;
        }
      }
      __syncthreads();
#pragma unroll
      for (int it = 0; it < 4; ++it) {
        const int i = (it * 512 + tid) * 4;
        const int lr = i >> 8;
        f32x4 v = *(const f32x4*)&ldsf[i ^ ((lr & 7) << 2)];
        *(f32x4*)(ob + H * 8192 + i) = v;
      }
      if (H == 0) __syncthreads();
    }
    // loop-top __syncthreads() (full vmcnt+lgkm drain) publishes staged X
  }
}

extern "C" void kernel_launch(void* const* d_in, const int* in_sizes, int n_in,
                              void* d_out, int out_size, void* d_ws, size_t ws_size,
                              hipStream_t stream) {
  (void)n_in; (void)ws_size; (void)out_size;
  const float* x     = (const float*)d_in[0];
  const float* wqkv  = (const float*)d_in[1];
  const float* bqkv  = (const float*)d_in[2];
  const float* wproj = (const float*)d_in[3];
  const float* bproj = (const float*)d_in[4];
  float* out = (float*)d_out;

  unsigned short* wsb = (unsigned short*)d_ws;
  const unsigned short* wq_bf = wsb;
  const unsigned short* wp_bf = wsb + NQKV;

  hipLaunchKernelGGL(ta_prep_weights, dim3(256), dim3(256), 0, stream, wqkv, wproj, wsb);

  const int bn_total = in_sizes[0] / SD;            // 2600
  const int nb = bn_total < 256 ? bn_total : 256;   // persistent, 1 block/CU
  hipLaunchKernelGGL(ta_fused_kernel, dim3(nb), dim3(512), 0, stream,
                     x, wq_bf, bqkv, wp_bf, bproj, out, bn_total, nb);
}

// Round 9
// 243.895 us; speedup vs baseline: 3.0874x; 3.0874x over previous
//
#include <hip/hip_runtime.h>
#include <hip/hip_bf16.h>

// TemporalAttention fused kernel for MI355X (gfx950), round 9.
// Diagnosis (R2/R4/R6 ~345us invariance): per-wave dependent 16B weight loads
// (64/wave/seq) hitting L3 (~600cy) serialize ~16us/block. Fix: block-
// cooperative double-buffered LDS staging of weights (T14 reg-staged, issue
// ks+2 during ks compute), merged Q/K/V ks-loop (shared X fragments), staged
// phaseC. All MFMA operands from LDS. LDS 128KB, 1 block/CU by design.

namespace {

constexpr int S_LEN = 64;
constexpr int DM    = 256;
constexpr int SD    = S_LEN * DM;
constexpr int NQKV  = 3 * DM * DM;

typedef float f32x4 __attribute__((ext_vector_type(4)));
typedef short s16x8 __attribute__((ext_vector_type(8)));

union BF2 { __hip_bfloat162 h; unsigned u; };
__device__ __forceinline__ unsigned pkbf2(float a, float b) {
  float2 t; t.x = a; t.y = b;
  BF2 cv; cv.h = __float22bfloat162_rn(t);
  return cv.u;
}

// In-register fragment transpose (verified rounds 3-8).
__device__ __forceinline__ s16x8 xpose_frag(f32x4 a0, f32x4 a1, int c, int g) {
  const int src0 = ((g & 1) << 5) + c;
  const int src1 = src0 + 16;
  unsigned p00 = pkbf2(a0[0], a0[1]);
  unsigned p01 = pkbf2(a0[2], a0[3]);
  unsigned p10 = pkbf2(a1[0], a1[1]);
  unsigned p11 = pkbf2(a1[2], a1[3]);
  const bool hi = (g & 2) != 0;
  unsigned w0a = (unsigned)__shfl((int)p00, src0);
  unsigned w0b = (unsigned)__shfl((int)p10, src0);
  unsigned w1a = (unsigned)__shfl((int)p01, src0);
  unsigned w1b = (unsigned)__shfl((int)p11, src0);
  unsigned w2a = (unsigned)__shfl((int)p00, src1);
  unsigned w2b = (unsigned)__shfl((int)p10, src1);
  unsigned w3a = (unsigned)__shfl((int)p01, src1);
  unsigned w3b = (unsigned)__shfl((int)p11, src1);
  union { s16x8 v; unsigned u[4]; } r;
  r.u[0] = hi ? w0b : w0a;
  r.u[1] = hi ? w1b : w1a;
  r.u[2] = hi ? w2b : w2a;
  r.u[3] = hi ? w3b : w3a;
  return r.v;
}

// Weight LDS addressing: per-ks image is [rows][32 cols] bf16, 64B/row.
// 16B-unit swizzle u' = g ^ ((row>>1)&3)  => 2-way bank aliasing (free, m136)
// for both the 16-consecutive-row compute reads and the staging writes.
__device__ __forceinline__ int wswz(int row, int g) {
  return row * 32 + ((g ^ ((row >> 1) & 3)) << 3);
}

} // namespace

// ---- prep: f32 weights -> bf16 in workspace ----
__global__ void ta_prep_weights(const float* __restrict__ wqkv,
                                const float* __restrict__ wproj,
                                unsigned short* __restrict__ wsb) {
  const int i = (blockIdx.x * 256 + (int)threadIdx.x) * 4;
  f32x4 v = (i < NQKV) ? *(const f32x4*)(wqkv + i)
                       : *(const f32x4*)(wproj + (i - NQKV));
  unsigned u0 = pkbf2(v[0], v[1]);
  unsigned u1 = pkbf2(v[2], v[3]);
  *(uint2*)(wsb + i) = make_uint2(u0, u1);
}

__global__ void __launch_bounds__(512, 1)
ta_fused_kernel(const float* __restrict__ x,
                const unsigned short* __restrict__ wq_bf,   // [768][256] bf16
                const float* __restrict__ bqkv,
                const unsigned short* __restrict__ wp_bf,   // [256][256] bf16
                const float* __restrict__ bproj,
                float* __restrict__ out)
{
  // LDS 128KB (65536 shorts):
  //  [0,16384)      xls[64][256] bf16 X (swizzled) -> att overlay
  //  [16384,40960)  W stage buffer 0 (48KB: [768][32] per-ks image)
  //  [40960,65536)  W stage buffer 1
  //  epilogue: f32 [32][256] overlay on buffer-0 region
  __shared__ __align__(16) unsigned short lds[65536];

  const int bn = blockIdx.x;
  const int tid = (int)threadIdx.x;
  const int w = tid >> 6;       // wave 0..7 = head
  const int l = tid & 63;
  const int g = l >> 4;
  const int c = l & 15;
  const int c7s = (c & 7) << 3;
  const int h = w;

  unsigned short* __restrict__ xls = lds;
  unsigned short* wbuf[2] = { lds + 16384, lds + 40960 };

  const float* __restrict__ xb = x + (size_t)bn * SD;

  // ---- issue W[ks=0] staging loads (fly under X stage) ----
  s16x8 wst[6];
#pragma unroll
  for (int i = 0; i < 6; ++i) {
    const int idx = i * 512 + tid, row = idx >> 2, gl = idx & 3;
    wst[i] = *(const s16x8*)&wq_bf[row * 256 + 0 * 32 + gl * 8];
  }

  // ---- stage X -> LDS bf16 (swizzled; verified R6) ----
#pragma unroll
  for (int it = 0; it < 4; ++it) {
    const int e = (it * 512 + tid) * 8;
    const int row = e >> 8;
    f32x4 a = *(const f32x4*)(xb + e);
    f32x4 b = *(const f32x4*)(xb + e + 4);
    union { s16x8 v; unsigned u[4]; } r;
    r.u[0] = pkbf2(a[0], a[1]); r.u[1] = pkbf2(a[2], a[3]);
    r.u[2] = pkbf2(b[0], b[1]); r.u[3] = pkbf2(b[2], b[3]);
    *(s16x8*)&xls[e ^ ((row & 7) << 3)] = r.v;
  }
  __syncthreads();                       // X visible; W bufs untouched yet

  // ---- W prologue: write buf0 = W[0]; issue W[1] ----
#pragma unroll
  for (int i = 0; i < 6; ++i) {
    const int idx = i * 512 + tid, row = idx >> 2, gl = idx & 3;
    *(s16x8*)&wbuf[0][wswz(row, gl)] = wst[i];
  }
#pragma unroll
  for (int i = 0; i < 6; ++i) {
    const int idx = i * 512 + tid, row = idx >> 2, gl = idx & 3;
    wst[i] = *(const s16x8*)&wq_bf[row * 256 + 1 * 32 + gl * 8];
  }
  __syncthreads();                       // buf0 ready

  // ---- merged sweep: Q,K,V over 8 ks-steps, weights from LDS ----
  f32x4 aq[2][4], ak[2][4], av[4][2];
#pragma unroll
  for (int t = 0; t < 2; ++t)
#pragma unroll
    for (int nj = 0; nj < 4; ++nj) {
      aq[t][nj] = f32x4{0.f, 0.f, 0.f, 0.f};
      ak[t][nj] = f32x4{0.f, 0.f, 0.f, 0.f};
    }
#pragma unroll
  for (int mt = 0; mt < 4; ++mt)
#pragma unroll
    for (int t = 0; t < 2; ++t) av[mt][t] = f32x4{0.f, 0.f, 0.f, 0.f};

#pragma unroll
  for (int ks = 0; ks < 8; ++ks) {
    const unsigned short* wb = wbuf[ks & 1];
    const int kof = ks * 32 + g * 8;
    s16x8 bx[4];
#pragma unroll
    for (int nj = 0; nj < 4; ++nj) {
      const int row = 16 * nj + c;
      bx[nj] = *(const s16x8*)&xls[(row * 256 + kof) ^ c7s];
    }
#pragma unroll
    for (int t = 0; t < 2; ++t) {
      s16x8 awq = *(const s16x8*)&wb[wswz((2 * h + t) * 16 + c, g)];
      s16x8 awk = *(const s16x8*)&wb[wswz(256 + 32 * h + 16 * t + c, g)];
      s16x8 awv = *(const s16x8*)&wb[wswz(512 + 32 * h + 16 * t + c, g)];
#pragma unroll
      for (int nj = 0; nj < 4; ++nj) {
        aq[t][nj] = __builtin_amdgcn_mfma_f32_16x16x32_bf16(awq, bx[nj], aq[t][nj], 0, 0, 0);
        ak[t][nj] = __builtin_amdgcn_mfma_f32_16x16x32_bf16(awk, bx[nj], ak[t][nj], 0, 0, 0);
        av[nj][t] = __builtin_amdgcn_mfma_f32_16x16x32_bf16(bx[nj], awv, av[nj][t], 0, 0, 0);
      }
    }
    if (ks < 7) {   // write next buffer (loaded one iteration ago)
#pragma unroll
      for (int i = 0; i < 6; ++i) {
        const int idx = i * 512 + tid, row = idx >> 2, gl = idx & 3;
        *(s16x8*)&wbuf[(ks + 1) & 1][wswz(row, gl)] = wst[i];
      }
    }
    if (ks < 6) {   // issue loads for ks+2
#pragma unroll
      for (int i = 0; i < 6; ++i) {
        const int idx = i * 512 + tid, row = idx >> 2, gl = idx & 3;
        wst[i] = *(const s16x8*)&wq_bf[row * 256 + (ks + 2) * 32 + gl * 8];
      }
    }
    __syncthreads();
  }

  // ---- issue phaseC W[0] loads early (fly under the attention middle) ----
  s16x8 pst[2];
#pragma unroll
  for (int i = 0; i < 2; ++i) {
    const int idx = i * 512 + tid, row = idx >> 2, gl = idx & 3;
    pst[i] = *(const s16x8*)&wp_bf[row * 256 + 0 * 32 + gl * 8];
  }

  // ---- biases ----
#pragma unroll
  for (int t = 0; t < 2; ++t) {
    f32x4 bq = *(const f32x4*)(bqkv + (2 * h + t) * 16 + 4 * g);
    f32x4 bk = *(const f32x4*)(bqkv + 256 + 32 * h + 16 * t + 4 * g);
#pragma unroll
    for (int nj = 0; nj < 4; ++nj) {
      aq[t][nj] += bq;
      ak[t][nj] += bk;
    }
  }
  {
    const float bv0 = bqkv[512 + 32 * h + c];
    const float bv1 = bqkv[512 + 32 * h + 16 + c];
#pragma unroll
    for (int mt = 0; mt < 4; ++mt)
#pragma unroll
      for (int r = 0; r < 4; ++r) {
        av[mt][0][r] += bv0;
        av[mt][1][r] += bv1;
      }
  }

  // ---- Q,K fragments (in-register transpose) ----
  s16x8 qa[4], ka[4];
#pragma unroll
  for (int i = 0; i < 4; ++i) {
    qa[i] = xpose_frag(aq[0][i], aq[1][i], c, g);
    ka[i] = xpose_frag(ak[0][i], ak[1][i], c, g);
  }

  // ---- S^T = K @ Q^T ----
  f32x4 sa[4][4];
#pragma unroll
  for (int ki = 0; ki < 4; ++ki)
#pragma unroll
    for (int qi = 0; qi < 4; ++qi) {
      f32x4 z = f32x4{0.f, 0.f, 0.f, 0.f};
      sa[ki][qi] = __builtin_amdgcn_mfma_f32_16x16x32_bf16(ka[ki], qa[qi], z, 0, 0, 0);
    }

  // ---- softmax over keys ----
  const float sc = 0.17677669529663687f * 1.4426950408889634f;
  float inv[4];
#pragma unroll
  for (int qi = 0; qi < 4; ++qi) {
    float m = sa[0][qi][0];
#pragma unroll
    for (int ki = 0; ki < 4; ++ki)
#pragma unroll
      for (int r = 0; r < 4; ++r) m = fmaxf(m, sa[ki][qi][r]);
    m = fmaxf(m, __shfl_xor(m, 16));
    m = fmaxf(m, __shfl_xor(m, 32));
    float s = 0.0f;
#pragma unroll
    for (int ki = 0; ki < 4; ++ki)
#pragma unroll
      for (int r = 0; r < 4; ++r) {
        float pv = exp2f((sa[ki][qi][r] - m) * sc);
        sa[ki][qi][r] = pv;
        s += pv;
      }
    s += __shfl_xor(s, 16);
    s += __shfl_xor(s, 32);
    inv[qi] = 1.0f / s;
  }

  // ---- P fragments ----
  s16x8 pa[4][2];
#pragma unroll
  for (int mi = 0; mi < 4; ++mi) {
    const float iv = inv[mi];
#pragma unroll
    for (int ks2 = 0; ks2 < 2; ++ks2) {
      f32x4 v0 = sa[2 * ks2][mi] * iv;
      f32x4 v1 = sa[2 * ks2 + 1][mi] * iv;
      pa[mi][ks2] = xpose_frag(v0, v1, c, g);
    }
  }

  // ---- V fragments ----
  s16x8 vb[2][2];
#pragma unroll
  for (int nd = 0; nd < 2; ++nd)
#pragma unroll
    for (int ks2 = 0; ks2 < 2; ++ks2)
      vb[nd][ks2] = xpose_frag(av[2 * ks2][nd], av[2 * ks2 + 1][nd], c, g);

  // ---- O = P @ V ----
  f32x4 oa[4][2];
#pragma unroll
  for (int mi = 0; mi < 4; ++mi)
#pragma unroll
    for (int nd = 0; nd < 2; ++nd) oa[mi][nd] = f32x4{0.f, 0.f, 0.f, 0.f};
#pragma unroll
  for (int ks2 = 0; ks2 < 2; ++ks2)
#pragma unroll
    for (int mi = 0; mi < 4; ++mi)
#pragma unroll
      for (int nd = 0; nd < 2; ++nd)
        oa[mi][nd] = __builtin_amdgcn_mfma_f32_16x16x32_bf16(pa[mi][ks2], vb[nd][ks2], oa[mi][nd], 0, 0, 0);

  unsigned obp[4][2][2];
#pragma unroll
  for (int mi = 0; mi < 4; ++mi)
#pragma unroll
    for (int nd = 0; nd < 2; ++nd) {
      obp[mi][nd][0] = pkbf2(oa[mi][nd][0], oa[mi][nd][1]);
      obp[mi][nd][1] = pkbf2(oa[mi][nd][2], oa[mi][nd][3]);
    }

  // ---- scatter att over X region; stage phaseC buf0; one barrier ----
#pragma unroll
  for (int mi = 0; mi < 4; ++mi)
#pragma unroll
    for (int nd = 0; nd < 2; ++nd)
#pragma unroll
      for (int r = 0; r < 4; ++r) {
        const int q = 16 * mi + 4 * g + r;
        const int feat = h * 32 + 16 * nd + c;
        unsigned val = obp[mi][nd][r >> 1] >> (16 * (r & 1));
        xls[(q * 256 + feat) ^ ((q & 7) << 3)] = (unsigned short)val;
      }
#pragma unroll
  for (int i = 0; i < 2; ++i) {
    const int idx = i * 512 + tid, row = idx >> 2, gl = idx & 3;
    *(s16x8*)&wbuf[0][wswz(row, gl)] = pst[i];
  }
#pragma unroll
  for (int i = 0; i < 2; ++i) {
    const int idx = i * 512 + tid, row = idx >> 2, gl = idx & 3;
    pst[i] = *(const s16x8*)&wp_bf[row * 256 + 1 * 32 + gl * 8];
  }
  __syncthreads();

  // ---- Phase C: out^T = Wproj @ att^T, weights from staged LDS ----
  f32x4 pacc[2][4];
#pragma unroll
  for (int ti = 0; ti < 2; ++ti)
#pragma unroll
    for (int nj = 0; nj < 4; ++nj) pacc[ti][nj] = f32x4{0.f, 0.f, 0.f, 0.f};

#pragma unroll
  for (int ks = 0; ks < 8; ++ks) {
    const unsigned short* wb = wbuf[ks & 1];
    const int kof = ks * 32 + 8 * g;
    s16x8 bx[4];
#pragma unroll
    for (int nj = 0; nj < 4; ++nj) {
      const int row = 16 * nj + c;
      bx[nj] = *(const s16x8*)&xls[(row * 256 + kof) ^ c7s];
    }
#pragma unroll
    for (int ti = 0; ti < 2; ++ti) {
      s16x8 aw = *(const s16x8*)&wb[wswz((2 * w + ti) * 16 + c, g)];
#pragma unroll
      for (int nj = 0; nj < 4; ++nj)
        pacc[ti][nj] = __builtin_amdgcn_mfma_f32_16x16x32_bf16(aw, bx[nj], pacc[ti][nj], 0, 0, 0);
    }
    if (ks < 7) {
#pragma unroll
      for (int i = 0; i < 2; ++i) {
        const int idx = i * 512 + tid, row = idx >> 2, gl = idx & 3;
        *(s16x8*)&wbuf[(ks + 1) & 1][wswz(row, gl)] = pst[i];
      }
    }
    if (ks < 6) {
#pragma unroll
      for (int i = 0; i < 2; ++i) {
        const int idx = i * 512 + tid, row = idx >> 2, gl = idx & 3;
        pst[i] = *(const s16x8*)&wp_bf[row * 256 + (ks + 2) * 32 + gl * 8];
      }
    }
    __syncthreads();
  }

  // ---- epilogue: two 32-row f32 halves (overlay W buf0), coalesced stores ----
  float* ldsf = (float*)wbuf[0];
  float* __restrict__ ob = out + (size_t)bn * SD;
#pragma unroll
  for (int H = 0; H < 2; ++H) {
#pragma unroll
    for (int ti = 0; ti < 2; ++ti) {
      const int e0 = (2 * w + ti) * 16 + 4 * g;
      f32x4 bp = *(const f32x4*)(bproj + e0);
#pragma unroll
      for (int nj = 2 * H; nj < 2 * H + 2; ++nj) {
        const int lr = 16 * (nj - 2 * H) + c;
        f32x4 v;
        v[0] = pacc[ti][nj][0] + bp[0];
        v[1] = pacc[ti][nj][1] + bp[1];
        v[2] = pacc[ti][nj][2] + bp[2];
        v[3] = pacc[ti][nj][3] + bp[3];
        *(f32x4*)&ldsf[(lr * 256 + e0) ^ ((lr & 7) << 2)] = v;
      }
    }
    __syncthreads();
#pragma unroll
    for (int it = 0; it < 4; ++it) {
      const int i = (it * 512 + tid) * 4;
      const int lr = i >> 8;
      f32x4 v = *(const f32x4*)&ldsf[i ^ ((lr & 7) << 2)];
      *(f32x4*)(ob + H * 8192 + i) = v;
    }
    if (H == 0) __syncthreads();
  }
}

extern "C" void kernel_launch(void* const* d_in, const int* in_sizes, int n_in,
                              void* d_out, int out_size, void* d_ws, size_t ws_size,
                              hipStream_t stream) {
  (void)n_in; (void)ws_size; (void)out_size;
  const float* x     = (const float*)d_in[0];
  const float* wqkv  = (const float*)d_in[1];
  const float* bqkv  = (const float*)d_in[2];
  const float* wproj = (const float*)d_in[3];
  const float* bproj = (const float*)d_in[4];
  float* out = (float*)d_out;

  unsigned short* wsb = (unsigned short*)d_ws;
  const unsigned short* wq_bf = wsb;
  const unsigned short* wp_bf = wsb + NQKV;

  hipLaunchKernelGGL(ta_prep_weights, dim3(256), dim3(256), 0, stream, wqkv, wproj, wsb);

  const int bn_total = in_sizes[0] / SD;  // 2600
  hipLaunchKernelGGL(ta_fused_kernel, dim3(bn_total), dim3(512), 0, stream,
                     x, wq_bf, bqkv, wp_bf, bproj, out);
}